// Round 3
// baseline (1083.384 us; speedup 1.0000x reference)
//
#include <hip/hip_runtime.h>
#include <stdint.h>

typedef __attribute__((ext_vector_type(8))) short short8;
typedef __attribute__((ext_vector_type(4))) short short4v;
typedef __attribute__((ext_vector_type(4))) float f32x4;

#define DEVINL __device__ __forceinline__

DEVINL unsigned short f2bf(float x) {
  uint32_t b = __float_as_uint(x);
  b += 0x7fffu + ((b >> 16) & 1u);
  return (unsigned short)(b >> 16);
}
DEVINL float bf2f(unsigned short u) {
  return __uint_as_float(((uint32_t)u) << 16);
}

DEVINL void gll16(const void* g, void* l) {
  __builtin_amdgcn_global_load_lds(
      (const __attribute__((address_space(1))) uint32_t*)g,
      (__attribute__((address_space(3))) uint32_t*)l, 16, 0, 0);
}

__global__ void cvt_w_bf16(const float* __restrict__ in,
                           unsigned short* __restrict__ out, int n) {
  int i = blockIdx.x * blockDim.x + threadIdx.x;
  int stride = gridDim.x * blockDim.x;
  for (; i < n; i += stride) out[i] = f2bf(in[i]);
}

// wave-per-row: out_row = bf16(in_row / (||in_row|| + eps))
template <int D>
__global__ __launch_bounds__(256) void norm_rows_f32(
    const float* __restrict__ in, unsigned short* __restrict__ out, int nrows) {
  const int lane = threadIdx.x & 63;
  const int row = blockIdx.x * 4 + (threadIdx.x >> 6);
  if (row >= nrows) return;
  const float* r = in + (size_t)row * D;
  constexpr int NSEG = D / 256;
  f32x4 v[NSEG];
  float ssq = 0.f;
#pragma unroll
  for (int i = 0; i < NSEG; ++i) {
    v[i] = *(const f32x4*)(r + (i * 64 + lane) * 4);
#pragma unroll
    for (int j = 0; j < 4; ++j) ssq += v[i][j] * v[i][j];
  }
#pragma unroll
  for (int m = 32; m >= 1; m >>= 1) ssq += __shfl_xor(ssq, m, 64);
  const float sc = 1.0f / (sqrtf(ssq) + 1e-8f);
  unsigned short* o = out + (size_t)row * D;
#pragma unroll
  for (int i = 0; i < NSEG; ++i) {
    short4v u;
#pragma unroll
    for (int j = 0; j < 4; ++j) u[j] = (short)f2bf(v[i][j] * sc);
    *(short4v*)(o + (i * 64 + lane) * 4) = u;
  }
}

// wave-per-row: scale[row] = 1/(||bf16 row|| + eps)
template <int H>
__global__ __launch_bounds__(256) void rownorm_bf16(
    const unsigned short* __restrict__ in, float* __restrict__ scale, int nrows) {
  const int lane = threadIdx.x & 63;
  const int row = blockIdx.x * 4 + (threadIdx.x >> 6);
  if (row >= nrows) return;
  const unsigned short* r = in + (size_t)row * H;
  constexpr int NSEG = H / 512;
  float ssq = 0.f;
#pragma unroll
  for (int i = 0; i < NSEG; ++i) {
    short8 u = *(const short8*)(r + (i * 64 + lane) * 8);
#pragma unroll
    for (int j = 0; j < 8; ++j) {
      float f = bf2f((unsigned short)u[j]);
      ssq += f * f;
    }
  }
#pragma unroll
  for (int m = 32; m >= 1; m >>= 1) ssq += __shfl_xor(ssq, m, 64);
  if (lane == 0) scale[row] = 1.0f / (sqrtf(ssq) + 1e-8f);
}

// Phased GEMM: C = epi(A[M,K]*Bw[N,K]^T). BM=BN=128, BK=128 as 4 K-slice
// phases of 32. 8 waves (2x4), per-wave C = 64x32. Dbuf LDS (128 KiB),
// counted vmcnt(6), raw s_barrier per phase, T2 k-unit swizzle, T5 setprio.
// Race-freedom: slice p of tile t is staged at phase p of tile t-1 (4 phases
// = 8 loads before first read); each phase's vmcnt(6) leaves <=3 newer slices
// outstanding, so the slice read NEXT phase is complete; per-phase barrier
// publishes cross-wave (staging wave's vmcnt executes before its barrier).
template <bool SCALE, bool RELU, bool OUT_BF16>
__global__ __launch_bounds__(512) void gemm_ph(
    const unsigned short* __restrict__ A, const unsigned short* __restrict__ Bw,
    const float* __restrict__ bias, const float* __restrict__ scaleArr,
    void* __restrict__ Cptr, int M, int N, int K) {
  __shared__ short ldsbuf[65536];  // As[2][4][128][32] | Bs[2][4][128][32]
  short* As = ldsbuf;
  short* Bs = ldsbuf + 32768;

  const int t = threadIdx.x;
  const int lane = t & 63;
  const int wid = t >> 6;   // 0..7
  const int wr = wid >> 2;  // 0..1  (M half)
  const int wc = wid & 3;   // 0..3  (N quarter)

  const int nwg = gridDim.x;
  const int bid = blockIdx.x;
  int wg = bid;
  if ((nwg & 7) == 0) wg = (bid & 7) * (nwg >> 3) + (bid >> 3);
  const int numBN = N >> 7;
  const int bm = wg / numBN;
  const int bn = wg % numBN;

  // Staging: wave w stages 16-row block w of each slice (1 KiB per gll16).
  // LDS is linear within the block: lane i -> row w*16+(i>>2), k-unit pos i&3.
  // Swizzle (both sides): stored k-unit u at position p satisfies
  // p = u ^ ((row>>1)&3)  -> pre-swizzle the GLOBAL source k.
  const int rStg = wid * 16 + (lane >> 2);
  const int kStg = (((lane & 3) ^ ((lane >> 3) & 3)) << 3);  // ((rStg>>1)&3)=(lane>>3)&3
  const unsigned short* srcA = A + (size_t)(bm * 128 + rStg) * K + kStg;
  const unsigned short* srcB = Bw + (size_t)(bn * 128 + rStg) * K + kStg;
  const int ldsStg = wid * 512;  // shorts within a slice

  // ds_read: frag row r, want k-unit q=lane>>4 -> read pos q ^ ((r>>1)&3);
  // ((r>>1)&3) == ((lane>>1)&3) since r = base16 + (lane&15).
  const int uRd = (((lane >> 4) ^ ((lane >> 1) & 3)) << 3);
  int offA[4], offB[2];
#pragma unroll
  for (int m = 0; m < 4; ++m)
    offA[m] = (wr * 64 + m * 16 + (lane & 15)) * 32 + uRd;
#pragma unroll
  for (int n = 0; n < 2; ++n)
    offB[n] = (wc * 32 + n * 16 + (lane & 15)) * 32 + uRd;

  f32x4 acc[4][2] = {};

  const int nt = K >> 7;
  // prologue: stage tile 0 (slices 0..3) into buf 0
#pragma unroll
  for (int s = 0; s < 4; ++s) {
    gll16(srcA + s * 32, &As[s * 4096 + ldsStg]);
    gll16(srcB + s * 32, &Bs[s * 4096 + ldsStg]);
  }
  asm volatile("s_waitcnt vmcnt(6)" ::: "memory");  // slice 0 complete
  asm volatile("s_barrier" ::: "memory");

  for (int tt = 0; tt < nt; ++tt) {
    const int cb = (tt & 1) << 14;  // current buf (shorts)
    const int nb = cb ^ 16384;      // next buf
    // last tile: wrap-stage tile 0 (data unused; keeps vmcnt uniform, in-bounds)
    const size_t kn = (size_t)((tt + 1 == nt) ? 0 : (tt + 1)) << 7;
#pragma unroll
    for (int s = 0; s < 4; ++s) {
      gll16(srcA + kn + s * 32, &As[nb + s * 4096 + ldsStg]);
      gll16(srcB + kn + s * 32, &Bs[nb + s * 4096 + ldsStg]);
      asm volatile("s_waitcnt vmcnt(6)" ::: "memory");
      const int so = cb + s * 4096;
      short8 a0 = *(const short8*)&As[so + offA[0]];
      short8 a1 = *(const short8*)&As[so + offA[1]];
      short8 a2 = *(const short8*)&As[so + offA[2]];
      short8 a3 = *(const short8*)&As[so + offA[3]];
      short8 b0 = *(const short8*)&Bs[so + offB[0]];
      short8 b1 = *(const short8*)&Bs[so + offB[1]];
      __builtin_amdgcn_s_setprio(1);
      acc[0][0] = __builtin_amdgcn_mfma_f32_16x16x32_bf16(a0, b0, acc[0][0], 0, 0, 0);
      acc[0][1] = __builtin_amdgcn_mfma_f32_16x16x32_bf16(a0, b1, acc[0][1], 0, 0, 0);
      acc[1][0] = __builtin_amdgcn_mfma_f32_16x16x32_bf16(a1, b0, acc[1][0], 0, 0, 0);
      acc[1][1] = __builtin_amdgcn_mfma_f32_16x16x32_bf16(a1, b1, acc[1][1], 0, 0, 0);
      acc[2][0] = __builtin_amdgcn_mfma_f32_16x16x32_bf16(a2, b0, acc[2][0], 0, 0, 0);
      acc[2][1] = __builtin_amdgcn_mfma_f32_16x16x32_bf16(a2, b1, acc[2][1], 0, 0, 0);
      acc[3][0] = __builtin_amdgcn_mfma_f32_16x16x32_bf16(a3, b0, acc[3][0], 0, 0, 0);
      acc[3][1] = __builtin_amdgcn_mfma_f32_16x16x32_bf16(a3, b1, acc[3][1], 0, 0, 0);
      __builtin_amdgcn_s_setprio(0);
      asm volatile("s_barrier" ::: "memory");
    }
  }
  asm volatile("s_waitcnt vmcnt(0)" ::: "memory");  // drain wrap-stage before end

  // epilogue: frag row=(lane>>4)*4+j, col=lane&15
#pragma unroll
  for (int m = 0; m < 4; ++m) {
#pragma unroll
    for (int j = 0; j < 4; ++j) {
      const int rl = wr * 64 + m * 16 + ((lane >> 4) << 2) + j;
      const size_t row = (size_t)bm * 128 + rl;
      float sc = 1.0f;
      if constexpr (SCALE) sc = scaleArr[row];
#pragma unroll
      for (int n = 0; n < 2; ++n) {
        const int col = bn * 128 + wc * 32 + n * 16 + (lane & 15);
        float v = acc[m][n][j];
        if constexpr (SCALE) v *= sc;
        v += bias[col];
        if constexpr (RELU) v = fmaxf(v, 0.f);
        if constexpr (OUT_BF16)
          ((unsigned short*)Cptr)[row * (size_t)N + col] = f2bf(v);
        else
          ((float*)Cptr)[row * (size_t)N + col] = v;
      }
    }
  }
}

// 2-phase GEMM kept for G3 (tiny-N, memory-bound)
template <int BM, int BN, int WN, bool SCALE, bool RELU, bool OUT_BF16>
__global__ __launch_bounds__(256) void gemm_ff(
    const unsigned short* __restrict__ A, const unsigned short* __restrict__ Bw,
    const float* __restrict__ bias, const float* __restrict__ scaleArr,
    void* __restrict__ Cptr, int M, int N, int K) {
  constexpr int BK = 32;
  constexpr int PTA = BM / 64;
  constexpr int PTB = BN / 64;
  __shared__ short As[BM * BK];
  __shared__ short Bs[BN * BK];

  const int t = threadIdx.x;
  const int lane = t & 63;
  const int wid = t >> 6;
  const int wr = wid / WN;
  const int wc = wid % WN;
  const int bm = blockIdx.x;
  const int bn = blockIdx.y;

  f32x4 acc[4][4] = {};
  const unsigned short* Abase = A + (size_t)bm * BM * K;
  const unsigned short* Bbase = Bw + (size_t)bn * BN * K;
  const int kIters = K / BK;
  for (int kk = 0; kk < kIters; ++kk) {
    const int k0 = kk * BK;
#pragma unroll
    for (int r = 0; r < PTB; ++r) {
      const int s = r * 256 + t;
      gll16(Bbase + (size_t)(s >> 2) * K + k0 + (s & 3) * 8, &Bs[s * 8]);
    }
#pragma unroll
    for (int r = 0; r < PTA; ++r) {
      const int s = r * 256 + t;
      gll16(Abase + (size_t)(s >> 2) * K + k0 + (s & 3) * 8, &As[s * 8]);
    }
    __syncthreads();
    short8 af[4], bfg[4];
#pragma unroll
    for (int m = 0; m < 4; ++m)
      af[m] = *(const short8*)&As[(wr * 64 + m * 16 + (lane & 15)) * BK + ((lane >> 4) * 8)];
#pragma unroll
    for (int n = 0; n < 4; ++n)
      bfg[n] = *(const short8*)&Bs[(wc * 64 + n * 16 + (lane & 15)) * BK + ((lane >> 4) * 8)];
#pragma unroll
    for (int m = 0; m < 4; ++m)
#pragma unroll
      for (int n = 0; n < 4; ++n)
        acc[m][n] = __builtin_amdgcn_mfma_f32_16x16x32_bf16(af[m], bfg[n], acc[m][n], 0, 0, 0);
    __syncthreads();
  }

#pragma unroll
  for (int m = 0; m < 4; ++m) {
#pragma unroll
    for (int j = 0; j < 4; ++j) {
      const int rl = wr * 64 + m * 16 + ((lane >> 4) << 2) + j;
      const size_t row = (size_t)bm * BM + rl;
      float sc = 1.0f;
      if constexpr (SCALE) sc = scaleArr[row];
#pragma unroll
      for (int n = 0; n < 4; ++n) {
        const int col = bn * BN + wc * 64 + n * 16 + (lane & 15);
        float v = acc[m][n][j];
        if constexpr (SCALE) v *= sc;
        v += bias[col];
        if constexpr (RELU) v = fmaxf(v, 0.f);
        if constexpr (OUT_BF16)
          ((unsigned short*)Cptr)[row * (size_t)N + col] = f2bf(v);
        else
          ((float*)Cptr)[row * (size_t)N + col] = v;
      }
    }
  }
}

extern "C" void kernel_launch(void* const* d_in, const int* in_sizes, int n_in,
                              void* d_out, int out_size, void* d_ws, size_t ws_size,
                              hipStream_t stream) {
  const float* states = (const float*)d_in[0];
  const float* W1 = (const float*)d_in[1];
  const float* b1 = (const float*)d_in[2];
  const float* W2 = (const float*)d_in[3];
  const float* b2 = (const float*)d_in[4];
  const float* Wq = (const float*)d_in[5];
  const float* bq = (const float*)d_in[6];
  float* out = (float*)d_out;

  const int D = 1024, H1 = 2048, H2 = 1024, AO = 64;
  const int B = in_sizes[0] / D;

  unsigned short* W1b = (unsigned short*)d_ws;  // [H1][D]
  unsigned short* W2b = W1b + (size_t)H1 * D;   // [H2][H1]
  unsigned short* Wqb = W2b + (size_t)H2 * H1;  // [AO][H2]
  char* dynbase = (char*)(Wqb + (size_t)AO * H2);

  const size_t wbytes = ((size_t)H1 * D + (size_t)H2 * H1 + (size_t)AO * H2) * 2;
  size_t avail = ws_size > wbytes ? ws_size - wbytes : 0;
  const size_t per_row = 4 + (size_t)(D + H1 + H2) * 2;
  long long bc = (long long)(avail / per_row);
  bc = (bc / 256) * 256;
  if (bc <= 0) bc = 256;
  if (bc > B) bc = B;

  float* scale1 = (float*)dynbase;
  unsigned short* sn = (unsigned short*)(scale1 + bc);
  unsigned short* h1 = sn + (size_t)bc * D;
  unsigned short* h2 = h1 + (size_t)bc * H1;

  cvt_w_bf16<<<dim3(1024), dim3(256), 0, stream>>>(W1, W1b, H1 * D);
  cvt_w_bf16<<<dim3(1024), dim3(256), 0, stream>>>(W2, W2b, H2 * H1);
  cvt_w_bf16<<<dim3(64), dim3(256), 0, stream>>>(Wq, Wqb, AO * H2);

  for (int off = 0; off < B; off += (int)bc) {
    const int cur = (B - off) < (int)bc ? (B - off) : (int)bc;
    norm_rows_f32<1024><<<dim3(cur / 4), dim3(256), 0, stream>>>(
        states + (size_t)off * D, sn, cur);
    // G1: h1 = relu(sn·W1^T + b1)
    gemm_ph<false, true, true>
        <<<dim3((cur / 128) * (H1 / 128)), dim3(512), 0, stream>>>(
            sn, W1b, b1, nullptr, h1, cur, H1, D);
    rownorm_bf16<2048><<<dim3(cur / 4), dim3(256), 0, stream>>>(h1, scale1, cur);
    // G2: h2 = relu(scale1·(h1·W2^T) + b2)
    gemm_ph<true, true, true>
        <<<dim3((cur / 128) * (H2 / 128)), dim3(512), 0, stream>>>(
            h1, W2b, b2, scale1, h2, cur, H2, H1);
    // G3: q = h2·Wq^T + bq
    gemm_ff<256, 64, 1, false, false, false>
        <<<dim3(cur / 256), dim3(256), 0, stream>>>(
            h2, Wqb, bq, nullptr, out + (size_t)off * AO, cur, AO, H2);
  }
}

// Round 4
// 964.921 us; speedup vs baseline: 1.1228x; 1.1228x over previous
//
#include <hip/hip_runtime.h>
#include <stdint.h>

typedef __attribute__((ext_vector_type(8))) short short8;
typedef __attribute__((ext_vector_type(4))) short short4v;
typedef __attribute__((ext_vector_type(4))) float f32x4;

#define DEVINL __device__ __forceinline__

DEVINL unsigned short f2bf(float x) {
  uint32_t b = __float_as_uint(x);
  b += 0x7fffu + ((b >> 16) & 1u);
  return (unsigned short)(b >> 16);
}
DEVINL float bf2f(unsigned short u) {
  return __uint_as_float(((uint32_t)u) << 16);
}

DEVINL void gll16(const void* g, void* l) {
  __builtin_amdgcn_global_load_lds(
      (const __attribute__((address_space(1))) uint32_t*)g,
      (__attribute__((address_space(3))) uint32_t*)l, 16, 0, 0);
}

__global__ void cvt_w_bf16(const float* __restrict__ in,
                           unsigned short* __restrict__ out, int n) {
  int i = blockIdx.x * blockDim.x + threadIdx.x;
  int stride = gridDim.x * blockDim.x;
  for (; i < n; i += stride) out[i] = f2bf(in[i]);
}

// wave-per-row: out_row = bf16(in_row / (||in_row|| + eps))
template <int D>
__global__ __launch_bounds__(256) void norm_rows_f32(
    const float* __restrict__ in, unsigned short* __restrict__ out, int nrows) {
  const int lane = threadIdx.x & 63;
  const int row = blockIdx.x * 4 + (threadIdx.x >> 6);
  if (row >= nrows) return;
  const float* r = in + (size_t)row * D;
  constexpr int NSEG = D / 256;
  f32x4 v[NSEG];
  float ssq = 0.f;
#pragma unroll
  for (int i = 0; i < NSEG; ++i) {
    v[i] = *(const f32x4*)(r + (i * 64 + lane) * 4);
#pragma unroll
    for (int j = 0; j < 4; ++j) ssq += v[i][j] * v[i][j];
  }
#pragma unroll
  for (int m = 32; m >= 1; m >>= 1) ssq += __shfl_xor(ssq, m, 64);
  const float sc = 1.0f / (sqrtf(ssq) + 1e-8f);
  unsigned short* o = out + (size_t)row * D;
#pragma unroll
  for (int i = 0; i < NSEG; ++i) {
    short4v u;
#pragma unroll
    for (int j = 0; j < 4; ++j) u[j] = (short)f2bf(v[i][j] * sc);
    *(short4v*)(o + (i * 64 + lane) * 4) = u;
  }
}

// Prefetched GEMM: C = epi(A[M,K]*Bw[N,K]^T). BM=BN=128, BK=64 (one stage
// phase per tile, rows = 128B full lines). 8 waves (2x4), per-wave C=64x32.
// Dbuf LDS 64KB -> 2 blocks/CU. Per tile: stage(t+1) -> vmcnt(4) -> barrier
// -> 12 ds_read_b128 -> 16 MFMA -> barrier. T2 16B-unit XOR swizzle
// (pre-swizzled global source, swizzled ds_read). T5 setprio around MFMA.
// Race-freedom: tile t's 4 loads issued during iter t-1; at iter t the
// vmcnt(4) (outstanding = 4 old + 4 just-issued) drains exactly tile t's
// loads; barrier publishes cross-wave. Buf (t+1)&1 was last READ at iter
// t-1 whose reads retired (lgkmcnt before MFMA) before its closing barrier.
// ACC_SSQ: atomically accumulate sum of squares of (post-epilogue) row values
// into ssqArr. SSQ_SCALE: multiply row by 1/(sqrt(ssqArr[row])+1e-8).
template <bool ACC_SSQ, bool SSQ_SCALE, bool RELU, bool OUT_BF16>
__global__ __launch_bounds__(512) void gemm_ph2(
    const unsigned short* __restrict__ A, const unsigned short* __restrict__ Bw,
    const float* __restrict__ bias, float* __restrict__ ssqArr,
    void* __restrict__ Cptr, int M, int N, int K) {
  __shared__ short lds[32768];  // As[2][128][64] | Bs[2][128][64]
  short* As = lds;
  short* Bs = lds + 16384;

  const int t = threadIdx.x;
  const int lane = t & 63;
  const int wid = t >> 6;   // 0..7
  const int wr = wid >> 2;  // 0..1
  const int wc = wid & 3;   // 0..3

  const int nwg = gridDim.x;
  const int bid = blockIdx.x;
  int wg = bid;
  if ((nwg & 7) == 0) wg = (bid & 7) * (nwg >> 3) + (bid >> 3);
  const int numBN = N >> 7;
  const int bm = wg / numBN;
  const int bn = wg % numBN;

  // Staging map: segment s = j*512 + t -> row = s>>3 (j=0:0..63, j=1:64..127),
  // 16B-unit position p = s&7. Stored unit at pos p is global unit p^(row&7)
  // (pre-swizzled source; LDS stays linear in s => gll16-compatible).
  const int row0 = t >> 3;
  const int usrc = ((t & 7) ^ (row0 & 7)) << 3;  // element offset of unit
  const unsigned short* sA0 = A + (size_t)(bm * 128 + row0) * K + usrc;
  const unsigned short* sA1 = A + (size_t)(bm * 128 + 64 + row0) * K + usrc;
  const unsigned short* sB0 = Bw + (size_t)(bn * 128 + row0) * K + usrc;
  const unsigned short* sB1 = Bw + (size_t)(bn * 128 + 64 + row0) * K + usrc;
  const int d0 = t * 8;         // LDS dst (shorts) for j=0
  const int d1 = 4096 + t * 8;  // j=1

  // ds_read: operand row r, global unit u=ks*4+(lane>>4) -> pos u^(r&7);
  // r&7 == lane&7 for all frags (frag bases are multiples of 16).
  const int sw = lane & 7;
  const int pA = (wr * 64 + (lane & 15)) * 64;
  const int pB = (wc * 32 + (lane & 15)) * 64;
  const int pu0 = (((lane >> 4)) ^ sw) * 8;
  const int pu1 = ((4 | (lane >> 4)) ^ sw) * 8;

  f32x4 acc[4][2] = {};
  const int nt = K >> 6;

  // prologue: stage tile 0 into buf 0
  gll16(sA0, &As[d0]);
  gll16(sA1, &As[d1]);
  gll16(sB0, &Bs[d0]);
  gll16(sB1, &Bs[d1]);

  for (int tt = 0; tt < nt; ++tt) {
    const int nb = ((tt + 1) & 1) * 8192;
    // wrap-stage tile 0 on last iter (in-bounds, data unused; uniform vmcnt)
    const int kn = ((tt + 1 == nt) ? 0 : (tt + 1)) * 64;
    gll16(sA0 + kn, &As[nb + d0]);
    gll16(sA1 + kn, &As[nb + d1]);
    gll16(sB0 + kn, &Bs[nb + d0]);
    gll16(sB1 + kn, &Bs[nb + d1]);
    asm volatile("s_waitcnt vmcnt(4)" ::: "memory");
    asm volatile("s_barrier" ::: "memory");
    const int cb = (tt & 1) * 8192;
    short8 a[4][2], b[2][2];
#pragma unroll
    for (int m = 0; m < 4; ++m) {
      a[m][0] = *(const short8*)&As[cb + pA + m * 1024 + pu0];
      a[m][1] = *(const short8*)&As[cb + pA + m * 1024 + pu1];
    }
#pragma unroll
    for (int n = 0; n < 2; ++n) {
      b[n][0] = *(const short8*)&Bs[cb + pB + n * 1024 + pu0];
      b[n][1] = *(const short8*)&Bs[cb + pB + n * 1024 + pu1];
    }
    __builtin_amdgcn_s_setprio(1);
#pragma unroll
    for (int ks = 0; ks < 2; ++ks)
#pragma unroll
      for (int m = 0; m < 4; ++m)
#pragma unroll
        for (int n = 0; n < 2; ++n)
          acc[m][n] = __builtin_amdgcn_mfma_f32_16x16x32_bf16(
              a[m][ks], b[n][ks], acc[m][n], 0, 0, 0);
    __builtin_amdgcn_s_setprio(0);
    asm volatile("s_barrier" ::: "memory");
  }
  asm volatile("s_waitcnt vmcnt(0)" ::: "memory");  // drain wrap-stage

  // epilogue: frag row=(lane>>4)*4+j, col=lane&15
#pragma unroll
  for (int m = 0; m < 4; ++m) {
#pragma unroll
    for (int j = 0; j < 4; ++j) {
      const int rl = wr * 64 + m * 16 + ((lane >> 4) << 2) + j;
      const size_t row = (size_t)bm * 128 + rl;
      float sc = 1.0f;
      if constexpr (SSQ_SCALE) sc = 1.0f / (sqrtf(ssqArr[row]) + 1e-8f);
      float v[2];
#pragma unroll
      for (int n = 0; n < 2; ++n) {
        const int col = bn * 128 + wc * 32 + n * 16 + (lane & 15);
        float x = acc[m][n][j];
        if constexpr (SSQ_SCALE) x *= sc;
        x += bias[col];
        if constexpr (RELU) x = fmaxf(x, 0.f);
        v[n] = x;
        if constexpr (OUT_BF16)
          ((unsigned short*)Cptr)[row * (size_t)N + col] = f2bf(x);
        else
          ((float*)Cptr)[row * (size_t)N + col] = x;
      }
      if constexpr (ACC_SSQ) {
        float part = v[0] * v[0] + v[1] * v[1];
        part += __shfl_xor(part, 1, 64);
        part += __shfl_xor(part, 2, 64);
        part += __shfl_xor(part, 4, 64);
        part += __shfl_xor(part, 8, 64);
        if ((lane & 15) == 0) atomicAdd(&ssqArr[row], part);
      }
    }
  }
}

// 2-phase GEMM for G3 (tiny-N, memory-bound)
template <int BM, int BN, int WN, bool SCALE, bool RELU, bool OUT_BF16>
__global__ __launch_bounds__(256) void gemm_ff(
    const unsigned short* __restrict__ A, const unsigned short* __restrict__ Bw,
    const float* __restrict__ bias, const float* __restrict__ scaleArr,
    void* __restrict__ Cptr, int M, int N, int K) {
  constexpr int BK = 32;
  constexpr int PTA = BM / 64;
  constexpr int PTB = BN / 64;
  __shared__ short As[BM * BK];
  __shared__ short Bs[BN * BK];

  const int t = threadIdx.x;
  const int lane = t & 63;
  const int wid = t >> 6;
  const int wr = wid / WN;
  const int wc = wid % WN;
  const int bm = blockIdx.x;
  const int bn = blockIdx.y;

  f32x4 acc[4][4] = {};
  const unsigned short* Abase = A + (size_t)bm * BM * K;
  const unsigned short* Bbase = Bw + (size_t)bn * BN * K;
  const int kIters = K / BK;
  for (int kk = 0; kk < kIters; ++kk) {
    const int k0 = kk * BK;
#pragma unroll
    for (int r = 0; r < PTB; ++r) {
      const int s = r * 256 + t;
      gll16(Bbase + (size_t)(s >> 2) * K + k0 + (s & 3) * 8, &Bs[s * 8]);
    }
#pragma unroll
    for (int r = 0; r < PTA; ++r) {
      const int s = r * 256 + t;
      gll16(Abase + (size_t)(s >> 2) * K + k0 + (s & 3) * 8, &As[s * 8]);
    }
    __syncthreads();
    short8 af[4], bfg[4];
#pragma unroll
    for (int m = 0; m < 4; ++m)
      af[m] = *(const short8*)&As[(wr * 64 + m * 16 + (lane & 15)) * BK + ((lane >> 4) * 8)];
#pragma unroll
    for (int n = 0; n < 4; ++n)
      bfg[n] = *(const short8*)&Bs[(wc * 64 + n * 16 + (lane & 15)) * BK + ((lane >> 4) * 8)];
#pragma unroll
    for (int m = 0; m < 4; ++m)
#pragma unroll
      for (int n = 0; n < 4; ++n)
        acc[m][n] = __builtin_amdgcn_mfma_f32_16x16x32_bf16(af[m], bfg[n], acc[m][n], 0, 0, 0);
    __syncthreads();
  }

#pragma unroll
  for (int m = 0; m < 4; ++m) {
#pragma unroll
    for (int j = 0; j < 4; ++j) {
      const int rl = wr * 64 + m * 16 + ((lane >> 4) << 2) + j;
      const size_t row = (size_t)bm * BM + rl;
      float sc = 1.0f;
      if constexpr (SCALE) sc = scaleArr[row];
#pragma unroll
      for (int n = 0; n < 4; ++n) {
        const int col = bn * BN + wc * 64 + n * 16 + (lane & 15);
        float v = acc[m][n][j];
        if constexpr (SCALE) v *= sc;
        v += bias[col];
        if constexpr (RELU) v = fmaxf(v, 0.f);
        if constexpr (OUT_BF16)
          ((unsigned short*)Cptr)[row * (size_t)N + col] = f2bf(v);
        else
          ((float*)Cptr)[row * (size_t)N + col] = v;
      }
    }
  }
}

extern "C" void kernel_launch(void* const* d_in, const int* in_sizes, int n_in,
                              void* d_out, int out_size, void* d_ws, size_t ws_size,
                              hipStream_t stream) {
  const float* states = (const float*)d_in[0];
  const float* W1 = (const float*)d_in[1];
  const float* b1 = (const float*)d_in[2];
  const float* W2 = (const float*)d_in[3];
  const float* b2 = (const float*)d_in[4];
  const float* Wq = (const float*)d_in[5];
  const float* bq = (const float*)d_in[6];
  float* out = (float*)d_out;

  const int D = 1024, H1 = 2048, H2 = 1024, AO = 64;
  const int B = in_sizes[0] / D;

  unsigned short* W1b = (unsigned short*)d_ws;  // [H1][D]
  unsigned short* W2b = W1b + (size_t)H1 * D;   // [H2][H1]
  unsigned short* Wqb = W2b + (size_t)H2 * H1;  // [AO][H2]
  char* dynbase = (char*)(Wqb + (size_t)AO * H2);

  const size_t wbytes = ((size_t)H1 * D + (size_t)H2 * H1 + (size_t)AO * H2) * 2;
  size_t avail = ws_size > wbytes ? ws_size - wbytes : 0;
  const size_t per_row = 4 + (size_t)(D + H1 + H2) * 2;
  long long bc = (long long)(avail / per_row);
  bc = (bc / 256) * 256;
  if (bc <= 0) bc = 256;
  if (bc > B) bc = B;

  float* ssq = (float*)dynbase;
  unsigned short* sn = (unsigned short*)(ssq + bc);
  unsigned short* h1 = sn + (size_t)bc * D;
  unsigned short* h2 = h1 + (size_t)bc * H1;

  cvt_w_bf16<<<dim3(1024), dim3(256), 0, stream>>>(W1, W1b, H1 * D);
  cvt_w_bf16<<<dim3(1024), dim3(256), 0, stream>>>(W2, W2b, H2 * H1);
  cvt_w_bf16<<<dim3(64), dim3(256), 0, stream>>>(Wq, Wqb, AO * H2);

  for (int off = 0; off < B; off += (int)bc) {
    const int cur = (B - off) < (int)bc ? (B - off) : (int)bc;
    norm_rows_f32<1024><<<dim3(cur / 4), dim3(256), 0, stream>>>(
        states + (size_t)off * D, sn, cur);
    hipMemsetAsync(ssq, 0, (size_t)cur * 4, stream);
    // G1: h1 = relu(sn·W1^T + b1), accumulating ssq of h1 rows
    gemm_ph2<true, false, true, true>
        <<<dim3((cur / 128) * (H1 / 128)), dim3(512), 0, stream>>>(
            sn, W1b, b1, ssq, h1, cur, H1, D);
    // G2: h2 = relu((1/(sqrt(ssq)+eps))·(h1·W2^T) + b2)
    gemm_ph2<false, true, true, true>
        <<<dim3((cur / 128) * (H2 / 128)), dim3(512), 0, stream>>>(
            h1, W2b, b2, ssq, h2, cur, H2, H1);
    // G3: q = h2·Wq^T + bq
    gemm_ff<256, 64, 1, false, false, false>
        <<<dim3(cur / 256), dim3(256), 0, stream>>>(
            h2, Wqb, bq, nullptr, out + (size_t)off * AO, cur, AO, H2);
  }
}

// Round 5
// 763.602 us; speedup vs baseline: 1.4188x; 1.2636x over previous
//
#include <hip/hip_runtime.h>
#include <stdint.h>

typedef __attribute__((ext_vector_type(8))) short short8;
typedef __attribute__((ext_vector_type(4))) short short4v;
typedef __attribute__((ext_vector_type(4))) float f32x4;

#define DEVINL __device__ __forceinline__

DEVINL unsigned short f2bf(float x) {
  uint32_t b = __float_as_uint(x);
  b += 0x7fffu + ((b >> 16) & 1u);
  return (unsigned short)(b >> 16);
}
DEVINL float bf2f(unsigned short u) {
  return __uint_as_float(((uint32_t)u) << 16);
}

DEVINL void gll16(const void* g, void* l) {
  __builtin_amdgcn_global_load_lds(
      (const __attribute__((address_space(1))) uint32_t*)g,
      (__attribute__((address_space(3))) uint32_t*)l, 16, 0, 0);
}

__global__ void cvt_w_bf16(const float* __restrict__ in,
                           unsigned short* __restrict__ out, int n) {
  int i = blockIdx.x * blockDim.x + threadIdx.x;
  int stride = gridDim.x * blockDim.x;
  for (; i < n; i += stride) out[i] = f2bf(in[i]);
}

// wave-per-row: out_row = bf16(in_row / (||in_row|| + eps))
template <int D>
__global__ __launch_bounds__(256) void norm_rows_f32(
    const float* __restrict__ in, unsigned short* __restrict__ out, int nrows) {
  const int lane = threadIdx.x & 63;
  const int row = blockIdx.x * 4 + (threadIdx.x >> 6);
  if (row >= nrows) return;
  const float* r = in + (size_t)row * D;
  constexpr int NSEG = D / 256;
  f32x4 v[NSEG];
  float ssq = 0.f;
#pragma unroll
  for (int i = 0; i < NSEG; ++i) {
    v[i] = *(const f32x4*)(r + (i * 64 + lane) * 4);
#pragma unroll
    for (int j = 0; j < 4; ++j) ssq += v[i][j] * v[i][j];
  }
#pragma unroll
  for (int m = 32; m >= 1; m >>= 1) ssq += __shfl_xor(ssq, m, 64);
  const float sc = 1.0f / (sqrtf(ssq) + 1e-8f);
  unsigned short* o = out + (size_t)row * D;
#pragma unroll
  for (int i = 0; i < NSEG; ++i) {
    short4v u;
#pragma unroll
    for (int j = 0; j < 4; ++j) u[j] = (short)f2bf(v[i][j] * sc);
    *(short4v*)(o + (i * 64 + lane) * 4) = u;
  }
}

// wave-per-row: scale[row] = 1/(||bf16 row|| + eps)
template <int H>
__global__ __launch_bounds__(256) void rownorm_bf16(
    const unsigned short* __restrict__ in, float* __restrict__ scale, int nrows) {
  const int lane = threadIdx.x & 63;
  const int row = blockIdx.x * 4 + (threadIdx.x >> 6);
  if (row >= nrows) return;
  const unsigned short* r = in + (size_t)row * H;
  constexpr int NSEG = H / 512;
  float ssq = 0.f;
#pragma unroll
  for (int i = 0; i < NSEG; ++i) {
    short8 u = *(const short8*)(r + (i * 64 + lane) * 8);
#pragma unroll
    for (int j = 0; j < 8; ++j) {
      float f = bf2f((unsigned short)u[j]);
      ssq += f * f;
    }
  }
#pragma unroll
  for (int m = 32; m >= 1; m >>= 1) ssq += __shfl_xor(ssq, m, 64);
  if (lane == 0) scale[row] = 1.0f / (sqrtf(ssq) + 1e-8f);
}

// Prefetched GEMM: C = epi(A[M,K]*Bw[N,K]^T). BM=BN=128, BK=64 (one stage
// phase per tile, rows = 128B full lines). 8 waves (2x4), per-wave C=64x32.
// Dbuf LDS 64KB -> 2 blocks/CU. Per tile: stage(t+1) -> vmcnt(4) -> barrier
// -> 12 ds_read_b128 -> 16 MFMA -> barrier. T2 16B-unit XOR swizzle
// (pre-swizzled global source, swizzled ds_read). T5 setprio around MFMA.
// Race-freedom: tile t's 4 loads issued during iter t-1; at iter t the
// vmcnt(4) (outstanding = 4 old + 4 just-issued) drains exactly tile t's
// loads; barrier publishes cross-wave. Buf (t+1)&1 was last READ at iter
// t-1 whose reads retired (lgkmcnt before MFMA) before its closing barrier.
// SCALE: multiply row by scaleArr[row] before bias (precomputed 1/(norm+eps)).
template <bool SCALE, bool RELU, bool OUT_BF16>
__global__ __launch_bounds__(512) void gemm_ph2(
    const unsigned short* __restrict__ A, const unsigned short* __restrict__ Bw,
    const float* __restrict__ bias, const float* __restrict__ scaleArr,
    void* __restrict__ Cptr, int M, int N, int K) {
  __shared__ short lds[32768];  // As[2][128][64] | Bs[2][128][64]
  short* As = lds;
  short* Bs = lds + 16384;

  const int t = threadIdx.x;
  const int lane = t & 63;
  const int wid = t >> 6;   // 0..7
  const int wr = wid >> 2;  // 0..1
  const int wc = wid & 3;   // 0..3

  const int nwg = gridDim.x;
  const int bid = blockIdx.x;
  int wg = bid;
  if ((nwg & 7) == 0) wg = (bid & 7) * (nwg >> 3) + (bid >> 3);
  const int numBN = N >> 7;
  const int bm = wg / numBN;
  const int bn = wg % numBN;

  // Staging map: segment s = j*512 + t -> row = s>>3 (j=0:0..63, j=1:64..127),
  // 16B-unit position p = s&7. Stored unit at pos p is global unit p^(row&7)
  // (pre-swizzled source; LDS stays linear in s => gll16-compatible).
  const int row0 = t >> 3;
  const int usrc = ((t & 7) ^ (row0 & 7)) << 3;  // element offset of unit
  const unsigned short* sA0 = A + (size_t)(bm * 128 + row0) * K + usrc;
  const unsigned short* sA1 = A + (size_t)(bm * 128 + 64 + row0) * K + usrc;
  const unsigned short* sB0 = Bw + (size_t)(bn * 128 + row0) * K + usrc;
  const unsigned short* sB1 = Bw + (size_t)(bn * 128 + 64 + row0) * K + usrc;
  const int d0 = t * 8;         // LDS dst (shorts) for j=0
  const int d1 = 4096 + t * 8;  // j=1

  // ds_read: operand row r, global unit u=ks*4+(lane>>4) -> pos u^(r&7);
  // r&7 == lane&7 for all frags (frag bases are multiples of 16).
  const int sw = lane & 7;
  const int pA = (wr * 64 + (lane & 15)) * 64;
  const int pB = (wc * 32 + (lane & 15)) * 64;
  const int pu0 = (((lane >> 4)) ^ sw) * 8;
  const int pu1 = ((4 | (lane >> 4)) ^ sw) * 8;

  f32x4 acc[4][2] = {};
  const int nt = K >> 6;

  // prologue: stage tile 0 into buf 0
  gll16(sA0, &As[d0]);
  gll16(sA1, &As[d1]);
  gll16(sB0, &Bs[d0]);
  gll16(sB1, &Bs[d1]);

  for (int tt = 0; tt < nt; ++tt) {
    const int nb = ((tt + 1) & 1) * 8192;
    // wrap-stage tile 0 on last iter (in-bounds, data unused; uniform vmcnt)
    const int kn = ((tt + 1 == nt) ? 0 : (tt + 1)) * 64;
    gll16(sA0 + kn, &As[nb + d0]);
    gll16(sA1 + kn, &As[nb + d1]);
    gll16(sB0 + kn, &Bs[nb + d0]);
    gll16(sB1 + kn, &Bs[nb + d1]);
    asm volatile("s_waitcnt vmcnt(4)" ::: "memory");
    asm volatile("s_barrier" ::: "memory");
    const int cb = (tt & 1) * 8192;
    short8 a[4][2], b[2][2];
#pragma unroll
    for (int m = 0; m < 4; ++m) {
      a[m][0] = *(const short8*)&As[cb + pA + m * 1024 + pu0];
      a[m][1] = *(const short8*)&As[cb + pA + m * 1024 + pu1];
    }
#pragma unroll
    for (int n = 0; n < 2; ++n) {
      b[n][0] = *(const short8*)&Bs[cb + pB + n * 1024 + pu0];
      b[n][1] = *(const short8*)&Bs[cb + pB + n * 1024 + pu1];
    }
    __builtin_amdgcn_s_setprio(1);
#pragma unroll
    for (int ks = 0; ks < 2; ++ks)
#pragma unroll
      for (int m = 0; m < 4; ++m)
#pragma unroll
        for (int n = 0; n < 2; ++n)
          acc[m][n] = __builtin_amdgcn_mfma_f32_16x16x32_bf16(
              a[m][ks], b[n][ks], acc[m][n], 0, 0, 0);
    __builtin_amdgcn_s_setprio(0);
    asm volatile("s_barrier" ::: "memory");
  }
  asm volatile("s_waitcnt vmcnt(0)" ::: "memory");  // drain wrap-stage

  // epilogue: frag row=(lane>>4)*4+j, col=lane&15
#pragma unroll
  for (int m = 0; m < 4; ++m) {
#pragma unroll
    for (int j = 0; j < 4; ++j) {
      const int rl = wr * 64 + m * 16 + ((lane >> 4) << 2) + j;
      const size_t row = (size_t)bm * 128 + rl;
      float sc = 1.0f;
      if constexpr (SCALE) sc = scaleArr[row];
#pragma unroll
      for (int n = 0; n < 2; ++n) {
        const int col = bn * 128 + wc * 32 + n * 16 + (lane & 15);
        float x = acc[m][n][j];
        if constexpr (SCALE) x *= sc;
        x += bias[col];
        if constexpr (RELU) x = fmaxf(x, 0.f);
        if constexpr (OUT_BF16)
          ((unsigned short*)Cptr)[row * (size_t)N + col] = f2bf(x);
        else
          ((float*)Cptr)[row * (size_t)N + col] = x;
      }
    }
  }
}

// 2-phase GEMM for G3 (tiny-N, memory-bound)
template <int BM, int BN, int WN, bool SCALE, bool RELU, bool OUT_BF16>
__global__ __launch_bounds__(256) void gemm_ff(
    const unsigned short* __restrict__ A, const unsigned short* __restrict__ Bw,
    const float* __restrict__ bias, const float* __restrict__ scaleArr,
    void* __restrict__ Cptr, int M, int N, int K) {
  constexpr int BK = 32;
  constexpr int PTA = BM / 64;
  constexpr int PTB = BN / 64;
  __shared__ short As[BM * BK];
  __shared__ short Bs[BN * BK];

  const int t = threadIdx.x;
  const int lane = t & 63;
  const int wid = t >> 6;
  const int wr = wid / WN;
  const int wc = wid % WN;
  const int bm = blockIdx.x;
  const int bn = blockIdx.y;

  f32x4 acc[4][4] = {};
  const unsigned short* Abase = A + (size_t)bm * BM * K;
  const unsigned short* Bbase = Bw + (size_t)bn * BN * K;
  const int kIters = K / BK;
  for (int kk = 0; kk < kIters; ++kk) {
    const int k0 = kk * BK;
#pragma unroll
    for (int r = 0; r < PTB; ++r) {
      const int s = r * 256 + t;
      gll16(Bbase + (size_t)(s >> 2) * K + k0 + (s & 3) * 8, &Bs[s * 8]);
    }
#pragma unroll
    for (int r = 0; r < PTA; ++r) {
      const int s = r * 256 + t;
      gll16(Abase + (size_t)(s >> 2) * K + k0 + (s & 3) * 8, &As[s * 8]);
    }
    __syncthreads();
    short8 af[4], bfg[4];
#pragma unroll
    for (int m = 0; m < 4; ++m)
      af[m] = *(const short8*)&As[(wr * 64 + m * 16 + (lane & 15)) * BK + ((lane >> 4) * 8)];
#pragma unroll
    for (int n = 0; n < 4; ++n)
      bfg[n] = *(const short8*)&Bs[(wc * 64 + n * 16 + (lane & 15)) * BK + ((lane >> 4) * 8)];
#pragma unroll
    for (int m = 0; m < 4; ++m)
#pragma unroll
      for (int n = 0; n < 4; ++n)
        acc[m][n] = __builtin_amdgcn_mfma_f32_16x16x32_bf16(af[m], bfg[n], acc[m][n], 0, 0, 0);
    __syncthreads();
  }

#pragma unroll
  for (int m = 0; m < 4; ++m) {
#pragma unroll
    for (int j = 0; j < 4; ++j) {
      const int rl = wr * 64 + m * 16 + ((lane >> 4) << 2) + j;
      const size_t row = (size_t)bm * BM + rl;
      float sc = 1.0f;
      if constexpr (SCALE) sc = scaleArr[row];
#pragma unroll
      for (int n = 0; n < 4; ++n) {
        const int col = bn * BN + wc * 64 + n * 16 + (lane & 15);
        float v = acc[m][n][j];
        if constexpr (SCALE) v *= sc;
        v += bias[col];
        if constexpr (RELU) v = fmaxf(v, 0.f);
        if constexpr (OUT_BF16)
          ((unsigned short*)Cptr)[row * (size_t)N + col] = f2bf(v);
        else
          ((float*)Cptr)[row * (size_t)N + col] = v;
      }
    }
  }
}

extern "C" void kernel_launch(void* const* d_in, const int* in_sizes, int n_in,
                              void* d_out, int out_size, void* d_ws, size_t ws_size,
                              hipStream_t stream) {
  const float* states = (const float*)d_in[0];
  const float* W1 = (const float*)d_in[1];
  const float* b1 = (const float*)d_in[2];
  const float* W2 = (const float*)d_in[3];
  const float* b2 = (const float*)d_in[4];
  const float* Wq = (const float*)d_in[5];
  const float* bq = (const float*)d_in[6];
  float* out = (float*)d_out;

  const int D = 1024, H1 = 2048, H2 = 1024, AO = 64;
  const int B = in_sizes[0] / D;

  unsigned short* W1b = (unsigned short*)d_ws;  // [H1][D]
  unsigned short* W2b = W1b + (size_t)H1 * D;   // [H2][H1]
  unsigned short* Wqb = W2b + (size_t)H2 * H1;  // [AO][H2]
  char* dynbase = (char*)(Wqb + (size_t)AO * H2);

  const size_t wbytes = ((size_t)H1 * D + (size_t)H2 * H1 + (size_t)AO * H2) * 2;
  size_t avail = ws_size > wbytes ? ws_size - wbytes : 0;
  const size_t per_row = 4 + (size_t)(D + H1 + H2) * 2;
  long long bc = (long long)(avail / per_row);
  bc = (bc / 256) * 256;
  if (bc <= 0) bc = 256;
  if (bc > B) bc = B;

  float* scale1 = (float*)dynbase;
  unsigned short* sn = (unsigned short*)(scale1 + bc);
  unsigned short* h1 = sn + (size_t)bc * D;
  unsigned short* h2 = h1 + (size_t)bc * H1;

  cvt_w_bf16<<<dim3(1024), dim3(256), 0, stream>>>(W1, W1b, H1 * D);
  cvt_w_bf16<<<dim3(1024), dim3(256), 0, stream>>>(W2, W2b, H2 * H1);
  cvt_w_bf16<<<dim3(64), dim3(256), 0, stream>>>(Wq, Wqb, AO * H2);

  for (int off = 0; off < B; off += (int)bc) {
    const int cur = (B - off) < (int)bc ? (B - off) : (int)bc;
    norm_rows_f32<1024><<<dim3(cur / 4), dim3(256), 0, stream>>>(
        states + (size_t)off * D, sn, cur);
    // G1: h1 = relu(sn·W1^T + b1)
    gemm_ph2<false, true, true>
        <<<dim3((cur / 128) * (H1 / 128)), dim3(512), 0, stream>>>(
            sn, W1b, b1, nullptr, h1, cur, H1, D);
    // scale1[row] = 1/(||h1 row||+eps)
    rownorm_bf16<2048><<<dim3(cur / 4), dim3(256), 0, stream>>>(h1, scale1, cur);
    // G2: h2 = relu(scale1·(h1·W2^T) + b2)
    gemm_ph2<true, true, true>
        <<<dim3((cur / 128) * (H2 / 128)), dim3(512), 0, stream>>>(
            h1, W2b, b2, scale1, h2, cur, H2, H1);
    // G3: q = h2·Wq^T + bq
    gemm_ff<256, 64, 1, false, false, false>
        <<<dim3(cur / 256), dim3(256), 0, stream>>>(
            h2, Wqb, bq, nullptr, out + (size_t)off * AO, cur, AO, H2);
  }
}

// Round 6
// 747.266 us; speedup vs baseline: 1.4498x; 1.0219x over previous
//
#include <hip/hip_runtime.h>
#include <stdint.h>

typedef __attribute__((ext_vector_type(8))) short short8;
typedef __attribute__((ext_vector_type(4))) short short4v;
typedef __attribute__((ext_vector_type(4))) float f32x4;

#define DEVINL __device__ __forceinline__

DEVINL unsigned short f2bf(float x) {
  uint32_t b = __float_as_uint(x);
  b += 0x7fffu + ((b >> 16) & 1u);
  return (unsigned short)(b >> 16);
}
DEVINL float bf2f(unsigned short u) {
  return __uint_as_float(((uint32_t)u) << 16);
}

DEVINL void gll16(const void* g, void* l) {
  __builtin_amdgcn_global_load_lds(
      (const __attribute__((address_space(1))) uint32_t*)g,
      (__attribute__((address_space(3))) uint32_t*)l, 16, 0, 0);
}

__global__ void cvt_w_bf16(const float* __restrict__ in,
                           unsigned short* __restrict__ out, int n) {
  int i = blockIdx.x * blockDim.x + threadIdx.x;
  int stride = gridDim.x * blockDim.x;
  for (; i < n; i += stride) out[i] = f2bf(in[i]);
}

// wave-per-row: out_row = bf16(in_row / (||in_row|| + eps))
template <int D>
__global__ __launch_bounds__(256) void norm_rows_f32(
    const float* __restrict__ in, unsigned short* __restrict__ out, int nrows) {
  const int lane = threadIdx.x & 63;
  const int row = blockIdx.x * 4 + (threadIdx.x >> 6);
  if (row >= nrows) return;
  const float* r = in + (size_t)row * D;
  constexpr int NSEG = D / 256;
  f32x4 v[NSEG];
  float ssq = 0.f;
#pragma unroll
  for (int i = 0; i < NSEG; ++i) {
    v[i] = *(const f32x4*)(r + (i * 64 + lane) * 4);
#pragma unroll
    for (int j = 0; j < 4; ++j) ssq += v[i][j] * v[i][j];
  }
#pragma unroll
  for (int m = 32; m >= 1; m >>= 1) ssq += __shfl_xor(ssq, m, 64);
  const float sc = 1.0f / (sqrtf(ssq) + 1e-8f);
  unsigned short* o = out + (size_t)row * D;
#pragma unroll
  for (int i = 0; i < NSEG; ++i) {
    short4v u;
#pragma unroll
    for (int j = 0; j < 4; ++j) u[j] = (short)f2bf(v[i][j] * sc);
    *(short4v*)(o + (i * 64 + lane) * 4) = u;
  }
}

// wave-per-row: scale[row] = 1/(||bf16 row|| + eps)
template <int H>
__global__ __launch_bounds__(256) void rownorm_bf16(
    const unsigned short* __restrict__ in, float* __restrict__ scale, int nrows) {
  const int lane = threadIdx.x & 63;
  const int row = blockIdx.x * 4 + (threadIdx.x >> 6);
  if (row >= nrows) return;
  const unsigned short* r = in + (size_t)row * H;
  constexpr int NSEG = H / 512;
  float ssq = 0.f;
#pragma unroll
  for (int i = 0; i < NSEG; ++i) {
    short8 u = *(const short8*)(r + (i * 64 + lane) * 8);
#pragma unroll
    for (int j = 0; j < 8; ++j) {
      float f = bf2f((unsigned short)u[j]);
      ssq += f * f;
    }
  }
#pragma unroll
  for (int m = 32; m >= 1; m >>= 1) ssq += __shfl_xor(ssq, m, 64);
  if (lane == 0) scale[row] = 1.0f / (sqrtf(ssq) + 1e-8f);
}

// 256x256 prefetched GEMM: C = epi(A[M,K]*Bw[N,K]^T). BK=64 (128B rows).
// 8 waves (2x4), per-wave C = 128x64 (acc 8x4 f32x4). Dbuf LDS 128 KiB
// (dynamic). Per iter: issue 8 gll16 for tile t+1 -> vmcnt(8) (counted,
// never 0 in loop; drains exactly tile t's 8 loads issued last iter) ->
// s_barrier -> 32 ds_read_b128 + 64 MFMA (setprio(1)) -> s_barrier.
// T2 involution swizzle: stored 16B-unit at pos p of row r is global unit
// p^(r&7) (pre-swizzled global source keeps LDS linear for gll16); ds_read
// uses pos u^(r&7). Quarter-wave bank analysis: 2 lanes/bank = free.
// Race-freedom: same argument as validated ph2 — reads of buf cb retire
// (lgkmcnt before MFMA consumption) before the closing barrier; writes to
// cb next iter are issued only after every wave passed that barrier.
template <bool SCALE, bool RELU, bool OUT_BF16>
__global__ __launch_bounds__(512, 1) void gemm_ph3(
    const unsigned short* __restrict__ A, const unsigned short* __restrict__ Bw,
    const float* __restrict__ bias, const float* __restrict__ scaleArr,
    void* __restrict__ Cptr, int M, int N, int K) {
  extern __shared__ __align__(16) short lds[];  // As[2][256][64] | Bs[2][256][64]
  short* As = lds;           // 2 x 16384 shorts
  short* Bs = lds + 32768;   // 2 x 16384 shorts

  const int t = threadIdx.x;
  const int lane = t & 63;
  const int wid = t >> 6;   // 0..7
  const int wr = wid >> 2;  // 0..1  (128-row half)
  const int wc = wid & 3;   // 0..3  (64-col quarter)

  const int nwg = gridDim.x;
  const int bid = blockIdx.x;
  int wg = bid;
  if ((nwg & 7) == 0) wg = (bid & 7) * (nwg >> 3) + (bid >> 3);
  const int numBN = N >> 8;
  const int bm = wg / numBN;
  const int bn = wg % numBN;

  // Staging: segment s = j*512 + t (j=0..3) -> row = s>>3 = t>>3 + j*64,
  // 16B-unit pos = t&7. Source pre-swizzle: global unit = (t&7)^(row&7),
  // row&7 = (t>>3)&7 for all j.
  const int row0 = t >> 3;
  const int usrc = ((t & 7) ^ (row0 & 7)) << 3;
  const unsigned short* sA0 = A + (size_t)(bm * 256 + row0) * K + usrc;
  const unsigned short* sA1 = A + (size_t)(bm * 256 + 64 + row0) * K + usrc;
  const unsigned short* sA2 = A + (size_t)(bm * 256 + 128 + row0) * K + usrc;
  const unsigned short* sA3 = A + (size_t)(bm * 256 + 192 + row0) * K + usrc;
  const unsigned short* sB0 = Bw + (size_t)(bn * 256 + row0) * K + usrc;
  const unsigned short* sB1 = Bw + (size_t)(bn * 256 + 64 + row0) * K + usrc;
  const unsigned short* sB2 = Bw + (size_t)(bn * 256 + 128 + row0) * K + usrc;
  const unsigned short* sB3 = Bw + (size_t)(bn * 256 + 192 + row0) * K + usrc;
  const int d0 = t * 8;
  const int d1 = 4096 + t * 8;
  const int d2 = 8192 + t * 8;
  const int d3 = 12288 + t * 8;

  // ds_read: row r, global unit u = ks*4+(lane>>4) -> pos u^(r&7);
  // r&7 == lane&7 (frag bases are multiples of 16).
  const int sw = lane & 7;
  const int pAw = (wr * 128 + (lane & 15)) * 64;
  const int pBw = (wc * 64 + (lane & 15)) * 64;
  const int pu0 = (((lane >> 4)) ^ sw) * 8;
  const int pu1 = ((4 | (lane >> 4)) ^ sw) * 8;

  f32x4 acc[8][4] = {};
  const int nt = K >> 6;

  // prologue: stage tile 0 into buf 0
  gll16(sA0, &As[d0]);
  gll16(sA1, &As[d1]);
  gll16(sA2, &As[d2]);
  gll16(sA3, &As[d3]);
  gll16(sB0, &Bs[d0]);
  gll16(sB1, &Bs[d1]);
  gll16(sB2, &Bs[d2]);
  gll16(sB3, &Bs[d3]);

  for (int tt = 0; tt < nt; ++tt) {
    const int nb = ((tt + 1) & 1) * 16384;
    // wrap-stage tile 0 on last iter (in-bounds, unused; uniform vmcnt)
    const int kn = ((tt + 1 == nt) ? 0 : (tt + 1)) * 64;
    gll16(sA0 + kn, &As[nb + d0]);
    gll16(sA1 + kn, &As[nb + d1]);
    gll16(sA2 + kn, &As[nb + d2]);
    gll16(sA3 + kn, &As[nb + d3]);
    gll16(sB0 + kn, &Bs[nb + d0]);
    gll16(sB1 + kn, &Bs[nb + d1]);
    gll16(sB2 + kn, &Bs[nb + d2]);
    gll16(sB3 + kn, &Bs[nb + d3]);
    asm volatile("s_waitcnt vmcnt(8)" ::: "memory");
    asm volatile("s_barrier" ::: "memory");
    const int cb = (tt & 1) * 16384;
    short8 b[4][2];
#pragma unroll
    for (int n = 0; n < 4; ++n) {
      b[n][0] = *(const short8*)&Bs[cb + pBw + n * 1024 + pu0];
      b[n][1] = *(const short8*)&Bs[cb + pBw + n * 1024 + pu1];
    }
    __builtin_amdgcn_s_setprio(1);
#pragma unroll
    for (int m = 0; m < 8; ++m) {
      const short8 a0 = *(const short8*)&As[cb + pAw + m * 1024 + pu0];
      const short8 a1 = *(const short8*)&As[cb + pAw + m * 1024 + pu1];
#pragma unroll
      for (int n = 0; n < 4; ++n) {
        acc[m][n] = __builtin_amdgcn_mfma_f32_16x16x32_bf16(a0, b[n][0], acc[m][n], 0, 0, 0);
        acc[m][n] = __builtin_amdgcn_mfma_f32_16x16x32_bf16(a1, b[n][1], acc[m][n], 0, 0, 0);
      }
    }
    __builtin_amdgcn_s_setprio(0);
    asm volatile("s_barrier" ::: "memory");
  }
  asm volatile("s_waitcnt vmcnt(0)" ::: "memory");  // drain wrap-stage

  // epilogue: frag row=(lane>>4)*4+j, col=lane&15
#pragma unroll
  for (int m = 0; m < 8; ++m) {
#pragma unroll
    for (int j = 0; j < 4; ++j) {
      const int rl = wr * 128 + m * 16 + ((lane >> 4) << 2) + j;
      const size_t row = (size_t)bm * 256 + rl;
      float sc = 1.0f;
      if constexpr (SCALE) sc = scaleArr[row];
#pragma unroll
      for (int n = 0; n < 4; ++n) {
        const int col = bn * 256 + wc * 64 + n * 16 + (lane & 15);
        float x = acc[m][n][j];
        if constexpr (SCALE) x *= sc;
        x += bias[col];
        if constexpr (RELU) x = fmaxf(x, 0.f);
        if constexpr (OUT_BF16)
          ((unsigned short*)Cptr)[row * (size_t)N + col] = f2bf(x);
        else
          ((float*)Cptr)[row * (size_t)N + col] = x;
      }
    }
  }
}

// 2-phase GEMM for G3 (tiny-N, memory-bound)
template <int BM, int BN, int WN, bool SCALE, bool RELU, bool OUT_BF16>
__global__ __launch_bounds__(256) void gemm_ff(
    const unsigned short* __restrict__ A, const unsigned short* __restrict__ Bw,
    const float* __restrict__ bias, const float* __restrict__ scaleArr,
    void* __restrict__ Cptr, int M, int N, int K) {
  constexpr int BK = 32;
  constexpr int PTA = BM / 64;
  constexpr int PTB = BN / 64;
  __shared__ short As[BM * BK];
  __shared__ short Bs[BN * BK];

  const int t = threadIdx.x;
  const int lane = t & 63;
  const int wid = t >> 6;
  const int wr = wid / WN;
  const int wc = wid % WN;
  const int bm = blockIdx.x;
  const int bn = blockIdx.y;

  f32x4 acc[4][4] = {};
  const unsigned short* Abase = A + (size_t)bm * BM * K;
  const unsigned short* Bbase = Bw + (size_t)bn * BN * K;
  const int kIters = K / BK;
  for (int kk = 0; kk < kIters; ++kk) {
    const int k0 = kk * BK;
#pragma unroll
    for (int r = 0; r < PTB; ++r) {
      const int s = r * 256 + t;
      gll16(Bbase + (size_t)(s >> 2) * K + k0 + (s & 3) * 8, &Bs[s * 8]);
    }
#pragma unroll
    for (int r = 0; r < PTA; ++r) {
      const int s = r * 256 + t;
      gll16(Abase + (size_t)(s >> 2) * K + k0 + (s & 3) * 8, &As[s * 8]);
    }
    __syncthreads();
    short8 af[4], bfg[4];
#pragma unroll
    for (int m = 0; m < 4; ++m)
      af[m] = *(const short8*)&As[(wr * 64 + m * 16 + (lane & 15)) * BK + ((lane >> 4) * 8)];
#pragma unroll
    for (int n = 0; n < 4; ++n)
      bfg[n] = *(const short8*)&Bs[(wc * 64 + n * 16 + (lane & 15)) * BK + ((lane >> 4) * 8)];
#pragma unroll
    for (int m = 0; m < 4; ++m)
#pragma unroll
      for (int n = 0; n < 4; ++n)
        acc[m][n] = __builtin_amdgcn_mfma_f32_16x16x32_bf16(af[m], bfg[n], acc[m][n], 0, 0, 0);
    __syncthreads();
  }

#pragma unroll
  for (int m = 0; m < 4; ++m) {
#pragma unroll
    for (int j = 0; j < 4; ++j) {
      const int rl = wr * 64 + m * 16 + ((lane >> 4) << 2) + j;
      const size_t row = (size_t)bm * BM + rl;
      float sc = 1.0f;
      if constexpr (SCALE) sc = scaleArr[row];
#pragma unroll
      for (int n = 0; n < 4; ++n) {
        const int col = bn * BN + wc * 64 + n * 16 + (lane & 15);
        float v = acc[m][n][j];
        if constexpr (SCALE) v *= sc;
        v += bias[col];
        if constexpr (RELU) v = fmaxf(v, 0.f);
        if constexpr (OUT_BF16)
          ((unsigned short*)Cptr)[row * (size_t)N + col] = f2bf(v);
        else
          ((float*)Cptr)[row * (size_t)N + col] = v;
      }
    }
  }
}

extern "C" void kernel_launch(void* const* d_in, const int* in_sizes, int n_in,
                              void* d_out, int out_size, void* d_ws, size_t ws_size,
                              hipStream_t stream) {
  const float* states = (const float*)d_in[0];
  const float* W1 = (const float*)d_in[1];
  const float* b1 = (const float*)d_in[2];
  const float* W2 = (const float*)d_in[3];
  const float* b2 = (const float*)d_in[4];
  const float* Wq = (const float*)d_in[5];
  const float* bq = (const float*)d_in[6];
  float* out = (float*)d_out;

  const int D = 1024, H1 = 2048, H2 = 1024, AO = 64;
  const int B = in_sizes[0] / D;

  unsigned short* W1b = (unsigned short*)d_ws;  // [H1][D]
  unsigned short* W2b = W1b + (size_t)H1 * D;   // [H2][H1]
  unsigned short* Wqb = W2b + (size_t)H2 * H1;  // [AO][H2]
  char* dynbase = (char*)(Wqb + (size_t)AO * H2);

  const size_t wbytes = ((size_t)H1 * D + (size_t)H2 * H1 + (size_t)AO * H2) * 2;
  size_t avail = ws_size > wbytes ? ws_size - wbytes : 0;
  const size_t per_row = 4 + (size_t)(D + H1 + H2) * 2;
  long long bc = (long long)(avail / per_row);
  bc = (bc / 256) * 256;
  if (bc <= 0) bc = 256;
  if (bc > B) bc = B;

  float* scale1 = (float*)dynbase;
  unsigned short* sn = (unsigned short*)(scale1 + bc);
  unsigned short* h1 = sn + (size_t)bc * D;
  unsigned short* h2 = h1 + (size_t)bc * H1;

  // allow 128 KiB dynamic LDS (host-side attribute set; capture-safe)
  (void)hipFuncSetAttribute((const void*)gemm_ph3<false, true, true>,
                            hipFuncAttributeMaxDynamicSharedMemorySize, 131072);
  (void)hipFuncSetAttribute((const void*)gemm_ph3<true, true, true>,
                            hipFuncAttributeMaxDynamicSharedMemorySize, 131072);

  cvt_w_bf16<<<dim3(1024), dim3(256), 0, stream>>>(W1, W1b, H1 * D);
  cvt_w_bf16<<<dim3(1024), dim3(256), 0, stream>>>(W2, W2b, H2 * H1);
  cvt_w_bf16<<<dim3(64), dim3(256), 0, stream>>>(Wq, Wqb, AO * H2);

  for (int off = 0; off < B; off += (int)bc) {
    const int cur = (B - off) < (int)bc ? (B - off) : (int)bc;
    norm_rows_f32<1024><<<dim3(cur / 4), dim3(256), 0, stream>>>(
        states + (size_t)off * D, sn, cur);
    // G1: h1 = relu(sn·W1^T + b1)
    gemm_ph3<false, true, true>
        <<<dim3((cur / 256) * (H1 / 256)), dim3(512), 131072, stream>>>(
            sn, W1b, b1, nullptr, h1, cur, H1, D);
    // scale1[row] = 1/(||h1 row||+eps)
    rownorm_bf16<2048><<<dim3(cur / 4), dim3(256), 0, stream>>>(h1, scale1, cur);
    // G2: h2 = relu(scale1·(h1·W2^T) + b2)
    gemm_ph3<true, true, true>
        <<<dim3((cur / 256) * (H2 / 256)), dim3(512), 131072, stream>>>(
            h1, W2b, b2, scale1, h2, cur, H2, H1);
    // G3: q = h2·Wq^T + bq
    gemm_ff<256, 64, 1, false, false, false>
        <<<dim3(cur / 256), dim3(256), 0, stream>>>(
            h2, Wqb, bq, nullptr, out + (size_t)off * AO, cur, AO, H2);
  }
}

// Round 7
// 707.499 us; speedup vs baseline: 1.5313x; 1.0562x over previous
//
#include <hip/hip_runtime.h>
#include <stdint.h>

typedef __attribute__((ext_vector_type(8))) short short8;
typedef __attribute__((ext_vector_type(4))) short short4v;
typedef __attribute__((ext_vector_type(4))) float f32x4;

#define DEVINL __device__ __forceinline__

DEVINL unsigned short f2bf(float x) {
  uint32_t b = __float_as_uint(x);
  b += 0x7fffu + ((b >> 16) & 1u);
  return (unsigned short)(b >> 16);
}
DEVINL float bf2f(unsigned short u) {
  return __uint_as_float(((uint32_t)u) << 16);
}

DEVINL void gll16(const void* g, void* l) {
  __builtin_amdgcn_global_load_lds(
      (const __attribute__((address_space(1))) uint32_t*)g,
      (__attribute__((address_space(3))) uint32_t*)l, 16, 0, 0);
}

__global__ void cvt_w_bf16(const float* __restrict__ in,
                           unsigned short* __restrict__ out, int n) {
  int i = blockIdx.x * blockDim.x + threadIdx.x;
  int stride = gridDim.x * blockDim.x;
  for (; i < n; i += stride) out[i] = f2bf(in[i]);
}

// wave-per-row: out_row = bf16(in_row / (||in_row|| + eps))
template <int D>
__global__ __launch_bounds__(256) void norm_rows_f32(
    const float* __restrict__ in, unsigned short* __restrict__ out, int nrows) {
  const int lane = threadIdx.x & 63;
  const int row = blockIdx.x * 4 + (threadIdx.x >> 6);
  if (row >= nrows) return;
  const float* r = in + (size_t)row * D;
  constexpr int NSEG = D / 256;
  f32x4 v[NSEG];
  float ssq = 0.f;
#pragma unroll
  for (int i = 0; i < NSEG; ++i) {
    v[i] = *(const f32x4*)(r + (i * 64 + lane) * 4);
#pragma unroll
    for (int j = 0; j < 4; ++j) ssq += v[i][j] * v[i][j];
  }
#pragma unroll
  for (int m = 32; m >= 1; m >>= 1) ssq += __shfl_xor(ssq, m, 64);
  const float sc = 1.0f / (sqrtf(ssq) + 1e-8f);
  unsigned short* o = out + (size_t)row * D;
#pragma unroll
  for (int i = 0; i < NSEG; ++i) {
    short4v u;
#pragma unroll
    for (int j = 0; j < 4; ++j) u[j] = (short)f2bf(v[i][j] * sc);
    *(short4v*)(o + (i * 64 + lane) * 4) = u;
  }
}

// wave-per-row: scale[row] = 1/(||bf16 row|| + eps)
template <int H>
__global__ __launch_bounds__(256) void rownorm_bf16(
    const unsigned short* __restrict__ in, float* __restrict__ scale, int nrows) {
  const int lane = threadIdx.x & 63;
  const int row = blockIdx.x * 4 + (threadIdx.x >> 6);
  if (row >= nrows) return;
  const unsigned short* r = in + (size_t)row * H;
  constexpr int NSEG = H / 512;
  float ssq = 0.f;
#pragma unroll
  for (int i = 0; i < NSEG; ++i) {
    short8 u = *(const short8*)(r + (i * 64 + lane) * 8);
#pragma unroll
    for (int j = 0; j < 8; ++j) {
      float f = bf2f((unsigned short)u[j]);
      ssq += f * f;
    }
  }
#pragma unroll
  for (int m = 32; m >= 1; m >>= 1) ssq += __shfl_xor(ssq, m, 64);
  if (lane == 0) scale[row] = 1.0f / (sqrtf(ssq) + 1e-8f);
}

// 256x256 4-phase GEMM (T3+T4): C = epi(A[M,K]*Bw[N,K]^T). BK=64, 8 waves
// (2x4), per-wave C = 128x64. Dbuf LDS 128 KiB. Each K-tile = 4 phases
// (mh,kh quadrants, 16 MFMA each): {ds_read quadrant frags; issue 4 gll16 of
// tile t+1 (phases 0,1 only); s_barrier; lgkmcnt(0)+sched_barrier (rule 18);
// setprio(1); 16 MFMA; setprio(0); s_barrier}. B-frags per kh read once,
// reused across both mh phases. vmcnt(0) only at tile boundary (issued >=2
// phases earlier => near-free). T2 involution swizzle as validated in r5/r6.
// Race-freedom: iter t reads ONLY buf cur, gll16 writes ONLY buf nxt;
// per-phase barriers are schedule-only. Boundary: phase-3 lgkmcnt(0) retires
// cur's reads before its closing barrier; vmcnt(0)+that barrier publish nxt
// before iter t+1's phase-0 reads; iter t+1's gll16s into cur are issued
// after the same barrier.
template <bool SCALE, bool RELU, bool OUT_BF16>
__global__ __launch_bounds__(512, 1) void gemm_ph4(
    const unsigned short* __restrict__ A, const unsigned short* __restrict__ Bw,
    const float* __restrict__ bias, const float* __restrict__ scaleArr,
    void* __restrict__ Cptr, int M, int N, int K) {
  extern __shared__ __align__(16) short lds[];  // As[2][256][64] | Bs[2][256][64]
  short* As = lds;          // 2 x 16384 shorts
  short* Bs = lds + 32768;  // 2 x 16384 shorts

  const int t = threadIdx.x;
  const int lane = t & 63;
  const int wid = t >> 6;   // 0..7
  const int wr = wid >> 2;  // 0..1  (128-row half)
  const int wc = wid & 3;   // 0..3  (64-col quarter)

  const int nwg = gridDim.x;
  const int bid = blockIdx.x;
  int wg = bid;
  if ((nwg & 7) == 0) wg = (bid & 7) * (nwg >> 3) + (bid >> 3);
  const int numBN = N >> 8;
  const int bm = wg / numBN;
  const int bn = wg % numBN;

  // Staging: segment s = j*512 + t (j=0..3) -> row = t>>3 + j*64, unit pos
  // t&7. Pre-swizzled source: global unit = (t&7)^(row&7), row&7=(t>>3)&7.
  const int row0 = t >> 3;
  const int usrc = ((t & 7) ^ (row0 & 7)) << 3;
  const unsigned short* sA0 = A + (size_t)(bm * 256 + row0) * K + usrc;
  const unsigned short* sA1 = A + (size_t)(bm * 256 + 64 + row0) * K + usrc;
  const unsigned short* sA2 = A + (size_t)(bm * 256 + 128 + row0) * K + usrc;
  const unsigned short* sA3 = A + (size_t)(bm * 256 + 192 + row0) * K + usrc;
  const unsigned short* sB0 = Bw + (size_t)(bn * 256 + row0) * K + usrc;
  const unsigned short* sB1 = Bw + (size_t)(bn * 256 + 64 + row0) * K + usrc;
  const unsigned short* sB2 = Bw + (size_t)(bn * 256 + 128 + row0) * K + usrc;
  const unsigned short* sB3 = Bw + (size_t)(bn * 256 + 192 + row0) * K + usrc;
  const int d0 = t * 8;
  const int d1 = 4096 + t * 8;
  const int d2 = 8192 + t * 8;
  const int d3 = 12288 + t * 8;

  // ds_read: row r, global unit u = kh*4+(lane>>4) -> pos u^(r&7); r&7==lane&7.
  const int sw = lane & 7;
  const int pAw = (wr * 128 + (lane & 15)) * 64;
  const int pBw = (wc * 64 + (lane & 15)) * 64;
  const int pu0 = (((lane >> 4)) ^ sw) * 8;
  const int pu1 = ((4 | (lane >> 4)) ^ sw) * 8;

  f32x4 acc[8][4] = {};
  const int nt = K >> 6;

  // prologue: stage tile 0 into buf 0, drain, publish
  gll16(sA0, &As[d0]);
  gll16(sA1, &As[d1]);
  gll16(sA2, &As[d2]);
  gll16(sA3, &As[d3]);
  gll16(sB0, &Bs[d0]);
  gll16(sB1, &Bs[d1]);
  gll16(sB2, &Bs[d2]);
  gll16(sB3, &Bs[d3]);
  asm volatile("s_waitcnt vmcnt(0)" ::: "memory");
  asm volatile("s_barrier" ::: "memory");

  for (int tt = 0; tt < nt; ++tt) {
    const int cb = (tt & 1) * 16384;
    const int nb = cb ^ 16384;
    const bool pf = (tt + 1 < nt);
    const int kn = (tt + 1) * 64;
    short8 b0_[4], b1_[4];
    // ---------- phase 0: (mh=0, kh=0) ----------
    {
      const short8 a0 = *(const short8*)&As[cb + pAw + 0 * 1024 + pu0];
      const short8 a1 = *(const short8*)&As[cb + pAw + 1 * 1024 + pu0];
      const short8 a2 = *(const short8*)&As[cb + pAw + 2 * 1024 + pu0];
      const short8 a3 = *(const short8*)&As[cb + pAw + 3 * 1024 + pu0];
#pragma unroll
      for (int n = 0; n < 4; ++n)
        b0_[n] = *(const short8*)&Bs[cb + pBw + n * 1024 + pu0];
      if (pf) {
        gll16(sA0 + kn, &As[nb + d0]);
        gll16(sA1 + kn, &As[nb + d1]);
        gll16(sA2 + kn, &As[nb + d2]);
        gll16(sA3 + kn, &As[nb + d3]);
      }
      asm volatile("s_barrier" ::: "memory");
      asm volatile("s_waitcnt lgkmcnt(0)" ::: "memory");
      __builtin_amdgcn_sched_barrier(0);
      __builtin_amdgcn_s_setprio(1);
#pragma unroll
      for (int n = 0; n < 4; ++n) {
        acc[0][n] = __builtin_amdgcn_mfma_f32_16x16x32_bf16(a0, b0_[n], acc[0][n], 0, 0, 0);
        acc[1][n] = __builtin_amdgcn_mfma_f32_16x16x32_bf16(a1, b0_[n], acc[1][n], 0, 0, 0);
        acc[2][n] = __builtin_amdgcn_mfma_f32_16x16x32_bf16(a2, b0_[n], acc[2][n], 0, 0, 0);
        acc[3][n] = __builtin_amdgcn_mfma_f32_16x16x32_bf16(a3, b0_[n], acc[3][n], 0, 0, 0);
      }
      __builtin_amdgcn_s_setprio(0);
      asm volatile("s_barrier" ::: "memory");
    }
    // ---------- phase 1: (mh=1, kh=0) ----------
    {
      const short8 a0 = *(const short8*)&As[cb + pAw + 4 * 1024 + pu0];
      const short8 a1 = *(const short8*)&As[cb + pAw + 5 * 1024 + pu0];
      const short8 a2 = *(const short8*)&As[cb + pAw + 6 * 1024 + pu0];
      const short8 a3 = *(const short8*)&As[cb + pAw + 7 * 1024 + pu0];
      if (pf) {
        gll16(sB0 + kn, &Bs[nb + d0]);
        gll16(sB1 + kn, &Bs[nb + d1]);
        gll16(sB2 + kn, &Bs[nb + d2]);
        gll16(sB3 + kn, &Bs[nb + d3]);
      }
      asm volatile("s_barrier" ::: "memory");
      asm volatile("s_waitcnt lgkmcnt(0)" ::: "memory");
      __builtin_amdgcn_sched_barrier(0);
      __builtin_amdgcn_s_setprio(1);
#pragma unroll
      for (int n = 0; n < 4; ++n) {
        acc[4][n] = __builtin_amdgcn_mfma_f32_16x16x32_bf16(a0, b0_[n], acc[4][n], 0, 0, 0);
        acc[5][n] = __builtin_amdgcn_mfma_f32_16x16x32_bf16(a1, b0_[n], acc[5][n], 0, 0, 0);
        acc[6][n] = __builtin_amdgcn_mfma_f32_16x16x32_bf16(a2, b0_[n], acc[6][n], 0, 0, 0);
        acc[7][n] = __builtin_amdgcn_mfma_f32_16x16x32_bf16(a3, b0_[n], acc[7][n], 0, 0, 0);
      }
      __builtin_amdgcn_s_setprio(0);
      asm volatile("s_barrier" ::: "memory");
    }
    // ---------- phase 2: (mh=0, kh=1) ----------
    {
      const short8 a0 = *(const short8*)&As[cb + pAw + 0 * 1024 + pu1];
      const short8 a1 = *(const short8*)&As[cb + pAw + 1 * 1024 + pu1];
      const short8 a2 = *(const short8*)&As[cb + pAw + 2 * 1024 + pu1];
      const short8 a3 = *(const short8*)&As[cb + pAw + 3 * 1024 + pu1];
#pragma unroll
      for (int n = 0; n < 4; ++n)
        b1_[n] = *(const short8*)&Bs[cb + pBw + n * 1024 + pu1];
      asm volatile("s_barrier" ::: "memory");
      asm volatile("s_waitcnt lgkmcnt(0)" ::: "memory");
      __builtin_amdgcn_sched_barrier(0);
      __builtin_amdgcn_s_setprio(1);
#pragma unroll
      for (int n = 0; n < 4; ++n) {
        acc[0][n] = __builtin_amdgcn_mfma_f32_16x16x32_bf16(a0, b1_[n], acc[0][n], 0, 0, 0);
        acc[1][n] = __builtin_amdgcn_mfma_f32_16x16x32_bf16(a1, b1_[n], acc[1][n], 0, 0, 0);
        acc[2][n] = __builtin_amdgcn_mfma_f32_16x16x32_bf16(a2, b1_[n], acc[2][n], 0, 0, 0);
        acc[3][n] = __builtin_amdgcn_mfma_f32_16x16x32_bf16(a3, b1_[n], acc[3][n], 0, 0, 0);
      }
      __builtin_amdgcn_s_setprio(0);
      asm volatile("s_barrier" ::: "memory");
    }
    // ---------- phase 3: (mh=1, kh=1) + boundary publish ----------
    {
      const short8 a0 = *(const short8*)&As[cb + pAw + 4 * 1024 + pu1];
      const short8 a1 = *(const short8*)&As[cb + pAw + 5 * 1024 + pu1];
      const short8 a2 = *(const short8*)&As[cb + pAw + 6 * 1024 + pu1];
      const short8 a3 = *(const short8*)&As[cb + pAw + 7 * 1024 + pu1];
      asm volatile("s_barrier" ::: "memory");
      asm volatile("s_waitcnt lgkmcnt(0)" ::: "memory");
      __builtin_amdgcn_sched_barrier(0);
      __builtin_amdgcn_s_setprio(1);
#pragma unroll
      for (int n = 0; n < 4; ++n) {
        acc[4][n] = __builtin_amdgcn_mfma_f32_16x16x32_bf16(a0, b1_[n], acc[4][n], 0, 0, 0);
        acc[5][n] = __builtin_amdgcn_mfma_f32_16x16x32_bf16(a1, b1_[n], acc[5][n], 0, 0, 0);
        acc[6][n] = __builtin_amdgcn_mfma_f32_16x16x32_bf16(a2, b1_[n], acc[6][n], 0, 0, 0);
        acc[7][n] = __builtin_amdgcn_mfma_f32_16x16x32_bf16(a3, b1_[n], acc[7][n], 0, 0, 0);
      }
      __builtin_amdgcn_s_setprio(0);
      asm volatile("s_waitcnt vmcnt(0)" ::: "memory");  // next tile staged (issued >=2 phases ago)
      asm volatile("s_barrier" ::: "memory");            // publish
    }
  }

  // epilogue: frag row=(lane>>4)*4+j, col=lane&15
#pragma unroll
  for (int m = 0; m < 8; ++m) {
#pragma unroll
    for (int j = 0; j < 4; ++j) {
      const int rl = wr * 128 + m * 16 + ((lane >> 4) << 2) + j;
      const size_t row = (size_t)bm * 256 + rl;
      float sc = 1.0f;
      if constexpr (SCALE) sc = scaleArr[row];
#pragma unroll
      for (int n = 0; n < 4; ++n) {
        const int col = bn * 256 + wc * 64 + n * 16 + (lane & 15);
        float x = acc[m][n][j];
        if constexpr (SCALE) x *= sc;
        x += bias[col];
        if constexpr (RELU) x = fmaxf(x, 0.f);
        if constexpr (OUT_BF16)
          ((unsigned short*)Cptr)[row * (size_t)N + col] = f2bf(x);
        else
          ((float*)Cptr)[row * (size_t)N + col] = x;
      }
    }
  }
}

// 2-phase GEMM for G3 (tiny-N, memory-bound)
template <int BM, int BN, int WN, bool SCALE, bool RELU, bool OUT_BF16>
__global__ __launch_bounds__(256) void gemm_ff(
    const unsigned short* __restrict__ A, const unsigned short* __restrict__ Bw,
    const float* __restrict__ bias, const float* __restrict__ scaleArr,
    void* __restrict__ Cptr, int M, int N, int K) {
  constexpr int BK = 32;
  constexpr int PTA = BM / 64;
  constexpr int PTB = BN / 64;
  __shared__ short As[BM * BK];
  __shared__ short Bs[BN * BK];

  const int t = threadIdx.x;
  const int lane = t & 63;
  const int wid = t >> 6;
  const int wr = wid / WN;
  const int wc = wid % WN;
  const int bm = blockIdx.x;
  const int bn = blockIdx.y;

  f32x4 acc[4][4] = {};
  const unsigned short* Abase = A + (size_t)bm * BM * K;
  const unsigned short* Bbase = Bw + (size_t)bn * BN * K;
  const int kIters = K / BK;
  for (int kk = 0; kk < kIters; ++kk) {
    const int k0 = kk * BK;
#pragma unroll
    for (int r = 0; r < PTB; ++r) {
      const int s = r * 256 + t;
      gll16(Bbase + (size_t)(s >> 2) * K + k0 + (s & 3) * 8, &Bs[s * 8]);
    }
#pragma unroll
    for (int r = 0; r < PTA; ++r) {
      const int s = r * 256 + t;
      gll16(Abase + (size_t)(s >> 2) * K + k0 + (s & 3) * 8, &As[s * 8]);
    }
    __syncthreads();
    short8 af[4], bfg[4];
#pragma unroll
    for (int m = 0; m < 4; ++m)
      af[m] = *(const short8*)&As[(wr * 64 + m * 16 + (lane & 15)) * BK + ((lane >> 4) * 8)];
#pragma unroll
    for (int n = 0; n < 4; ++n)
      bfg[n] = *(const short8*)&Bs[(wc * 64 + n * 16 + (lane & 15)) * BK + ((lane >> 4) * 8)];
#pragma unroll
    for (int m = 0; m < 4; ++m)
#pragma unroll
      for (int n = 0; n < 4; ++n)
        acc[m][n] = __builtin_amdgcn_mfma_f32_16x16x32_bf16(af[m], bfg[n], acc[m][n], 0, 0, 0);
    __syncthreads();
  }

#pragma unroll
  for (int m = 0; m < 4; ++m) {
#pragma unroll
    for (int j = 0; j < 4; ++j) {
      const int rl = wr * 64 + m * 16 + ((lane >> 4) << 2) + j;
      const size_t row = (size_t)bm * BM + rl;
      float sc = 1.0f;
      if constexpr (SCALE) sc = scaleArr[row];
#pragma unroll
      for (int n = 0; n < 4; ++n) {
        const int col = bn * BN + wc * 64 + n * 16 + (lane & 15);
        float v = acc[m][n][j];
        if constexpr (SCALE) v *= sc;
        v += bias[col];
        if constexpr (RELU) v = fmaxf(v, 0.f);
        if constexpr (OUT_BF16)
          ((unsigned short*)Cptr)[row * (size_t)N + col] = f2bf(v);
        else
          ((float*)Cptr)[row * (size_t)N + col] = v;
      }
    }
  }
}

extern "C" void kernel_launch(void* const* d_in, const int* in_sizes, int n_in,
                              void* d_out, int out_size, void* d_ws, size_t ws_size,
                              hipStream_t stream) {
  const float* states = (const float*)d_in[0];
  const float* W1 = (const float*)d_in[1];
  const float* b1 = (const float*)d_in[2];
  const float* W2 = (const float*)d_in[3];
  const float* b2 = (const float*)d_in[4];
  const float* Wq = (const float*)d_in[5];
  const float* bq = (const float*)d_in[6];
  float* out = (float*)d_out;

  const int D = 1024, H1 = 2048, H2 = 1024, AO = 64;
  const int B = in_sizes[0] / D;

  unsigned short* W1b = (unsigned short*)d_ws;  // [H1][D]
  unsigned short* W2b = W1b + (size_t)H1 * D;   // [H2][H1]
  unsigned short* Wqb = W2b + (size_t)H2 * H1;  // [AO][H2]
  char* dynbase = (char*)(Wqb + (size_t)AO * H2);

  const size_t wbytes = ((size_t)H1 * D + (size_t)H2 * H1 + (size_t)AO * H2) * 2;
  size_t avail = ws_size > wbytes ? ws_size - wbytes : 0;
  const size_t per_row = 4 + (size_t)(D + H1 + H2) * 2;
  long long bc = (long long)(avail / per_row);
  bc = (bc / 256) * 256;
  if (bc <= 0) bc = 256;
  if (bc > B) bc = B;

  float* scale1 = (float*)dynbase;
  unsigned short* sn = (unsigned short*)(scale1 + bc);
  unsigned short* h1 = sn + (size_t)bc * D;
  unsigned short* h2 = h1 + (size_t)bc * H1;

  // allow 128 KiB dynamic LDS (host-side attribute set; capture-safe)
  (void)hipFuncSetAttribute((const void*)gemm_ph4<false, true, true>,
                            hipFuncAttributeMaxDynamicSharedMemorySize, 131072);
  (void)hipFuncSetAttribute((const void*)gemm_ph4<true, true, true>,
                            hipFuncAttributeMaxDynamicSharedMemorySize, 131072);

  cvt_w_bf16<<<dim3(1024), dim3(256), 0, stream>>>(W1, W1b, H1 * D);
  cvt_w_bf16<<<dim3(1024), dim3(256), 0, stream>>>(W2, W2b, H2 * H1);
  cvt_w_bf16<<<dim3(64), dim3(256), 0, stream>>>(Wq, Wqb, AO * H2);

  for (int off = 0; off < B; off += (int)bc) {
    const int cur = (B - off) < (int)bc ? (B - off) : (int)bc;
    norm_rows_f32<1024><<<dim3(cur / 4), dim3(256), 0, stream>>>(
        states + (size_t)off * D, sn, cur);
    // G1: h1 = relu(sn·W1^T + b1)
    gemm_ph4<false, true, true>
        <<<dim3((cur / 256) * (H1 / 256)), dim3(512), 131072, stream>>>(
            sn, W1b, b1, nullptr, h1, cur, H1, D);
    // scale1[row] = 1/(||h1 row||+eps)
    rownorm_bf16<2048><<<dim3(cur / 4), dim3(256), 0, stream>>>(h1, scale1, cur);
    // G2: h2 = relu(scale1·(h1·W2^T) + b2)
    gemm_ph4<true, true, true>
        <<<dim3((cur / 256) * (H2 / 256)), dim3(512), 131072, stream>>>(
            h1, W2b, b2, scale1, h2, cur, H2, H1);
    // G3: q = h2·Wq^T + bq
    gemm_ff<256, 64, 1, false, false, false>
        <<<dim3(cur / 256), dim3(256), 0, stream>>>(
            h2, Wqb, bq, nullptr, out + (size_t)off * AO, cur, AO, H2);
  }
}